// Round 1
// baseline (7675.341 us; speedup 1.0000x reference)
//
#include <hip/hip_runtime.h>
#include <math.h>

#define SELU_ALPHA 1.6732632423543772f
#define SELU_SCALE 1.0507009873554805f

__device__ __forceinline__ float selu_f(float x) {
    return SELU_SCALE * (x > 0.f ? x : SELU_ALPHA * expm1f(x));
}

// ---- degree accumulation (float adds of 1.0 are exact for counts) ----
__global__ void degree_kernel(const int* __restrict__ src, const int* __restrict__ dst,
                              float* __restrict__ dout, float* __restrict__ din, int E) {
    int e = blockIdx.x * blockDim.x + threadIdx.x;
    if (e >= E) return;
    atomicAdd(&dout[src[e]], 1.f);
    atomicAdd(&din[dst[e]], 1.f);
}

__global__ void norm_kernel(float* __restrict__ v, int n) {
    int i = blockIdx.x * blockDim.x + threadIdx.x;
    if (i >= n) return;
    v[i] = 1.f / sqrtf(fmaxf(v[i], 1.f));
}

// ---- edge scatter: agg[dst] += x[src] * norm_out[src] ----
// TPE threads per edge, each handles 4 consecutive feats (float4).
template<int TPE>
__global__ void edge_agg_kernel(const float* __restrict__ x, const float* __restrict__ norm_out,
                                const int* __restrict__ src, const int* __restrict__ dst,
                                float* __restrict__ agg, int E) {
    const int FIN = TPE * 4;
    long long t = (long long)blockIdx.x * blockDim.x + threadIdx.x;
    int e = (int)(t / TPE);
    int j = (int)(t % TPE);
    if (e >= E) return;
    int s = src[e];
    int d = dst[e];
    float w = norm_out[s];
    float4 v = reinterpret_cast<const float4*>(x + (size_t)s * FIN)[j];
    float* o = agg + (size_t)d * FIN + 4 * j;
    atomicAdd(o + 0, v.x * w);
    atomicAdd(o + 1, v.y * w);
    atomicAdd(o + 2, v.z * w);
    atomicAdd(o + 3, v.w * w);
}

// ---- per-node dense: out[n] = act((agg[n]*norm_in[n]) @ W + b), FOUT=128 ----
// 256 threads: 2 nodes in flight, 128 output features each. W staged in LDS.
template<int FIN, bool SELU>
__global__ __launch_bounds__(256) void gemm_node_kernel(
        const float* __restrict__ agg, const float* __restrict__ norm_in,
        const float* __restrict__ W, const float* __restrict__ b,
        float* __restrict__ out, int n_nodes, int nodes_per_block) {
    __shared__ float sW[FIN * 128];
    __shared__ float sA[2][FIN];
    int tid = threadIdx.x;
    for (int i = tid; i < FIN * 128; i += 256) sW[i] = W[i];
    int half = tid >> 7;      // 0 or 1
    int o = tid & 127;        // output feature
    float bias = b[o];
    int base = blockIdx.x * nodes_per_block;
    __syncthreads();
    for (int n0 = 0; n0 < nodes_per_block; n0 += 2) {
        int n = base + n0 + half;
        bool valid = n < n_nodes;
        float nin = valid ? norm_in[n] : 0.f;
        for (int k = o; k < FIN; k += 128)
            sA[half][k] = valid ? agg[(size_t)n * FIN + k] * nin : 0.f;
        __syncthreads();
        float acc = bias;
        #pragma unroll
        for (int k = 0; k < FIN; ++k)
            acc += sA[half][k] * sW[k * 128 + o];
        if (valid) {
            if (SELU) acc = selu_f(acc);
            out[(size_t)n * 128 + o] = acc;
        }
        __syncthreads();
    }
}

// ---- graph readout: gsum[n2g[n]] += y[n] ----
__global__ void readout_kernel(const float* __restrict__ y, const int* __restrict__ n2g,
                               float* __restrict__ gsum, int n_nodes) {
    long long t = (long long)blockIdx.x * blockDim.x + threadIdx.x;
    int n = (int)(t >> 5);
    int j = (int)(t & 31);
    if (n >= n_nodes) return;
    int g = n2g[n];
    float4 v = reinterpret_cast<const float4*>(y + (size_t)n * 128)[j];
    float* o = gsum + (size_t)g * 128 + 4 * j;
    atomicAdd(o + 0, v.x);
    atomicAdd(o + 1, v.y);
    atomicAdd(o + 2, v.z);
    atomicAdd(o + 3, v.w);
}

// ---- MLP layer 1: [G,131] @ [131,256] + b, selu. One block (256 thr) per graph ----
__global__ __launch_bounds__(256) void mlp1_kernel(
        const float* __restrict__ gsum, const float* __restrict__ fg,
        const float* __restrict__ W, const float* __restrict__ b,
        float* __restrict__ y1, int G) {
    int g = blockIdx.x;
    int o = threadIdx.x;   // 0..255
    if (g >= G) return;
    float acc = b[o];
    const float* in = gsum + (size_t)g * 128;
    #pragma unroll 8
    for (int k = 0; k < 128; ++k) acc += in[k] * W[k * 256 + o];
    const float* fgr = fg + (size_t)g * 3;
    acc += fgr[0] * W[128 * 256 + o];
    acc += fgr[1] * W[129 * 256 + o];
    acc += fgr[2] * W[130 * 256 + o];
    y1[(size_t)g * 256 + o] = selu_f(acc);
}

// ---- MLP layer 2: [G,256] @ [256,128] + b, selu. One block (128 thr) per graph ----
__global__ __launch_bounds__(128) void mlp2_kernel(
        const float* __restrict__ y1, const float* __restrict__ W,
        const float* __restrict__ b, float* __restrict__ y2, int G) {
    int g = blockIdx.x;
    int o = threadIdx.x;   // 0..127
    if (g >= G) return;
    float acc = b[o];
    const float* in = y1 + (size_t)g * 256;
    #pragma unroll 8
    for (int k = 0; k < 256; ++k) acc += in[k] * W[k * 128 + o];
    y2[(size_t)g * 128 + o] = selu_f(acc);
}

// ---- MLP layer 3: [G,128] @ [128,1] + b -> out[g] ----
__global__ void mlp3_kernel(const float* __restrict__ y2, const float* __restrict__ W,
                            const float* __restrict__ b, float* __restrict__ out, int G) {
    int g = blockIdx.x * blockDim.x + threadIdx.x;
    if (g >= G) return;
    const float* in = y2 + (size_t)g * 128;
    float acc = b[0];
    #pragma unroll 8
    for (int k = 0; k < 128; ++k) acc += in[k] * W[k];
    out[g] = acc;
}

extern "C" void kernel_launch(void* const* d_in, const int* in_sizes, int n_in,
                              void* d_out, int out_size, void* d_ws, size_t ws_size,
                              hipStream_t stream) {
    const float* feats_node  = (const float*)d_in[0];   // [N,64]
    const float* feats_graph = (const float*)d_in[1];   // [G,3]
    const int*   src         = (const int*)d_in[2];     // [E]
    const int*   dst         = (const int*)d_in[3];     // [E]
    const int*   node2graph  = (const int*)d_in[4];     // [N]
    const float* W1 = (const float*)d_in[5];
    const float* b1 = (const float*)d_in[6];
    const float* W2 = (const float*)d_in[7];
    const float* b2 = (const float*)d_in[8];
    const float* W3 = (const float*)d_in[9];
    const float* b3 = (const float*)d_in[10];
    const float* L1w = (const float*)d_in[11];
    const float* L1b = (const float*)d_in[12];
    const float* L2w = (const float*)d_in[13];
    const float* L2b = (const float*)d_in[14];
    const float* L3w = (const float*)d_in[15];
    const float* L3b = (const float*)d_in[16];

    const int N = in_sizes[0] / 64;
    const int G = in_sizes[1] / 3;
    const int E = in_sizes[2];

    float* ws = (float*)d_ws;
    float* norm_out = ws;                      // N
    float* norm_in  = norm_out + N;            // N
    float* agg      = norm_in + N;             // N*128
    float* xbuf     = agg + (size_t)N * 128;   // N*128
    float* gsum     = xbuf + (size_t)N * 128;  // G*128
    float* y1       = gsum + (size_t)G * 128;  // G*256
    float* y2       = y1 + (size_t)G * 256;    // G*128

    float* out = (float*)d_out;

    // 1. degrees -> norms
    hipMemsetAsync(norm_out, 0, (size_t)2 * N * sizeof(float), stream);
    degree_kernel<<<(E + 255) / 256, 256, 0, stream>>>(src, dst, norm_out, norm_in, E);
    norm_kernel<<<(2 * N + 255) / 256, 256, 0, stream>>>(norm_out, 2 * N);

    const int NPB = 32;
    const int gemm_grid = (N + NPB - 1) / NPB;

    // 2. layer 1 (FIN=64)
    hipMemsetAsync(agg, 0, (size_t)N * 64 * sizeof(float), stream);
    {
        long long threads = (long long)E * 16;
        edge_agg_kernel<16><<<(unsigned)((threads + 255) / 256), 256, 0, stream>>>(
            feats_node, norm_out, src, dst, agg, E);
    }
    gemm_node_kernel<64, true><<<gemm_grid, 256, 0, stream>>>(
        agg, norm_in, W1, b1, xbuf, N, NPB);

    // 3. layer 2 (FIN=128)
    hipMemsetAsync(agg, 0, (size_t)N * 128 * sizeof(float), stream);
    {
        long long threads = (long long)E * 32;
        edge_agg_kernel<32><<<(unsigned)((threads + 255) / 256), 256, 0, stream>>>(
            xbuf, norm_out, src, dst, agg, E);
    }
    gemm_node_kernel<128, true><<<gemm_grid, 256, 0, stream>>>(
        agg, norm_in, W2, b2, xbuf, N, NPB);

    // 4. layer 3 (FIN=128, no selu)
    hipMemsetAsync(agg, 0, (size_t)N * 128 * sizeof(float), stream);
    {
        long long threads = (long long)E * 32;
        edge_agg_kernel<32><<<(unsigned)((threads + 255) / 256), 256, 0, stream>>>(
            xbuf, norm_out, src, dst, agg, E);
    }
    gemm_node_kernel<128, false><<<gemm_grid, 256, 0, stream>>>(
        agg, norm_in, W3, b3, xbuf, N, NPB);

    // 5. readout
    hipMemsetAsync(gsum, 0, (size_t)G * 128 * sizeof(float), stream);
    {
        long long threads = (long long)N * 32;
        readout_kernel<<<(unsigned)((threads + 255) / 256), 256, 0, stream>>>(
            xbuf, node2graph, gsum, N);
    }

    // 6. MLP head
    mlp1_kernel<<<G, 256, 0, stream>>>(gsum, feats_graph, L1w, L1b, y1, G);
    mlp2_kernel<<<G, 128, 0, stream>>>(y1, L2w, L2b, y2, G);
    mlp3_kernel<<<(G + 255) / 256, 256, 0, stream>>>(y2, L3w, L3b, out, G);
}

// Round 2
// 1109.923 us; speedup vs baseline: 6.9152x; 6.9152x over previous
//
#include <hip/hip_runtime.h>
#include <math.h>

#define SELU_ALPHA 1.6732632423543772f
#define SELU_SCALE 1.0507009873554805f

__device__ __forceinline__ float selu_f(float x) {
    return SELU_SCALE * (x > 0.f ? x : SELU_ALPHA * expm1f(x));
}

// ---- integer degree accumulation ----
__global__ void degree_kernel(const int* __restrict__ src, const int* __restrict__ dst,
                              int* __restrict__ dout, int* __restrict__ din, int E) {
    int e = blockIdx.x * blockDim.x + threadIdx.x;
    if (e >= E) return;
    atomicAdd(&dout[src[e]], 1);
    atomicAdd(&din[dst[e]], 1);
}

// norm[i] = 1/sqrt(max(deg,1)); processes 2N (out then in, contiguous)
__global__ void norm_kernel(const int* __restrict__ deg, float* __restrict__ norm, int n) {
    int i = blockIdx.x * blockDim.x + threadIdx.x;
    if (i >= n) return;
    norm[i] = 1.f / sqrtf(fmaxf((float)deg[i], 1.f));
}

// ---- exclusive scan of deg_in -> row_start (3 kernels) ----
#define SCAN_B 1024   // elements per block (256 thr x 4)

__global__ __launch_bounds__(256) void scan_block_sums(const int* __restrict__ in,
                                                       int* __restrict__ bsums, int n) {
    __shared__ int s[256];
    int b = blockIdx.x, t = threadIdx.x;
    int base = b * SCAN_B;
    int sum = 0;
    for (int i = t; i < SCAN_B; i += 256) {
        int idx = base + i;
        sum += (idx < n) ? in[idx] : 0;
    }
    s[t] = sum; __syncthreads();
    for (int off = 128; off > 0; off >>= 1) {
        if (t < off) s[t] += s[t + off];
        __syncthreads();
    }
    if (t == 0) bsums[b] = s[0];
}

__global__ __launch_bounds__(256) void scan_bsums(int* __restrict__ bsums, int nb) {
    __shared__ int s[256];
    __shared__ int carry_s;
    int t = threadIdx.x;
    if (t == 0) carry_s = 0;
    __syncthreads();
    for (int base = 0; base < nb; base += 256) {
        int idx = base + t;
        int v = (idx < nb) ? bsums[idx] : 0;
        s[t] = v; __syncthreads();
        for (int off = 1; off < 256; off <<= 1) {
            int x = (t >= off) ? s[t - off] : 0;
            __syncthreads();
            s[t] += x;
            __syncthreads();
        }
        int incl = s[t];
        int excl = incl - v;
        int c = carry_s;
        __syncthreads();
        if (idx < nb) bsums[idx] = c + excl;
        if (t == 255) carry_s = c + incl;
        __syncthreads();
    }
}

__global__ __launch_bounds__(256) void scan_apply(const int* __restrict__ in,
                                                  const int* __restrict__ boffs,
                                                  int* __restrict__ out, int n) {
    __shared__ int s[256];
    int b = blockIdx.x, t = threadIdx.x;
    int idx0 = b * SCAN_B + t * 4;
    int v[4]; int tsum = 0;
    #pragma unroll
    for (int k = 0; k < 4; ++k) {
        int idx = idx0 + k;
        v[k] = (idx < n) ? in[idx] : 0;
        tsum += v[k];
    }
    s[t] = tsum; __syncthreads();
    for (int off = 1; off < 256; off <<= 1) {
        int x = (t >= off) ? s[t - off] : 0;
        __syncthreads();
        s[t] += x;
        __syncthreads();
    }
    int run = s[t] - tsum + boffs[b];   // exclusive prefix for this thread's first elem
    #pragma unroll
    for (int k = 0; k < 4; ++k) {
        int idx = idx0 + k;
        if (idx < n) out[idx] = run;
        run += v[k];
    }
}

// ---- CSR fill: csr_src[row_start[dst]+rank] = src; csr_w = norm_out[src] ----
__global__ void csr_fill_kernel(const int* __restrict__ src, const int* __restrict__ dst,
                                const float* __restrict__ norm_out,
                                const int* __restrict__ row_start, int* __restrict__ cursor,
                                int* __restrict__ csr_src, float* __restrict__ csr_w, int E) {
    int e = blockIdx.x * blockDim.x + threadIdx.x;
    if (e >= E) return;
    int d = dst[e], s = src[e];
    int pos = row_start[d] + atomicAdd(&cursor[d], 1);
    csr_src[pos] = s;
    csr_w[pos] = norm_out[s];
}

// ---- gather-aggregate: agg[n] = sum_{e in CSR[n]} csr_w[e] * x[csr_src[e]] ----
// TPG threads per node, float4 each. No atomics, one coalesced write per row.
template<int TPG, int FIN>
__global__ __launch_bounds__(256) void csr_agg_kernel(
        const float* __restrict__ x, const int* __restrict__ row_start,
        const int* __restrict__ deg, const int* __restrict__ csr_src,
        const float* __restrict__ csr_w, float* __restrict__ agg, int N) {
    const int GPB = 256 / TPG;
    int g = threadIdx.x / TPG;
    int j = threadIdx.x % TPG;
    int n = blockIdx.x * GPB + g;
    if (n >= N) return;
    int beg = row_start[n];
    int end = beg + deg[n];
    float4 acc = make_float4(0.f, 0.f, 0.f, 0.f);
    for (int e = beg; e < end; ++e) {
        int s = csr_src[e];
        float w = csr_w[e];
        float4 v = reinterpret_cast<const float4*>(x + (size_t)s * FIN)[j];
        acc.x += v.x * w; acc.y += v.y * w; acc.z += v.z * w; acc.w += v.w * w;
    }
    reinterpret_cast<float4*>(agg + (size_t)n * FIN)[j] = acc;
}

// ---- per-node dense: out[n] = act((agg[n]*norm_in[n]) @ W + b), FOUT=128 ----
template<int FIN, bool SELU>
__global__ __launch_bounds__(256) void gemm_node_kernel(
        const float* __restrict__ agg, const float* __restrict__ norm_in,
        const float* __restrict__ W, const float* __restrict__ b,
        float* __restrict__ out, int n_nodes, int nodes_per_block) {
    __shared__ float sW[FIN * 128];
    __shared__ float sA[2][FIN];
    int tid = threadIdx.x;
    for (int i = tid; i < FIN * 128; i += 256) sW[i] = W[i];
    int half = tid >> 7;
    int o = tid & 127;
    float bias = b[o];
    int base = blockIdx.x * nodes_per_block;
    __syncthreads();
    for (int n0 = 0; n0 < nodes_per_block; n0 += 2) {
        int n = base + n0 + half;
        bool valid = n < n_nodes;
        float nin = valid ? norm_in[n] : 0.f;
        for (int k = o; k < FIN; k += 128)
            sA[half][k] = valid ? agg[(size_t)n * FIN + k] * nin : 0.f;
        __syncthreads();
        float acc = bias;
        #pragma unroll
        for (int k = 0; k < FIN; ++k)
            acc += sA[half][k] * sW[k * 128 + o];
        if (valid) {
            if (SELU) acc = selu_f(acc);
            out[(size_t)n * 128 + o] = acc;
        }
        __syncthreads();
    }
}

// ---- graph range starts via binary search (node2graph is sorted) ----
__global__ void graph_starts_kernel(const int* __restrict__ n2g, int* __restrict__ gstart,
                                    int N, int G) {
    int g = blockIdx.x * blockDim.x + threadIdx.x;
    if (g > G) return;
    int lo = 0, hi = N;
    while (lo < hi) {
        int mid = (lo + hi) >> 1;
        if (n2g[mid] < g) lo = mid + 1; else hi = mid;
    }
    gstart[g] = lo;
}

// ---- readout: gsum[g] = sum of y rows in [gstart[g], gstart[g+1]) ----
__global__ __launch_bounds__(128) void readout_kernel(
        const float* __restrict__ y, const int* __restrict__ gstart,
        float* __restrict__ gsum, int G) {
    int g = blockIdx.x;
    int o = threadIdx.x;   // 0..127
    if (g >= G) return;
    int beg = gstart[g], end = gstart[g + 1];
    float acc = 0.f;
    for (int n = beg; n < end; ++n)
        acc += y[(size_t)n * 128 + o];
    gsum[(size_t)g * 128 + o] = acc;
}

// ---- MLP layers ----
__global__ __launch_bounds__(256) void mlp1_kernel(
        const float* __restrict__ gsum, const float* __restrict__ fg,
        const float* __restrict__ W, const float* __restrict__ b,
        float* __restrict__ y1, int G) {
    int g = blockIdx.x;
    int o = threadIdx.x;
    if (g >= G) return;
    float acc = b[o];
    const float* in = gsum + (size_t)g * 128;
    #pragma unroll 8
    for (int k = 0; k < 128; ++k) acc += in[k] * W[k * 256 + o];
    const float* fgr = fg + (size_t)g * 3;
    acc += fgr[0] * W[128 * 256 + o];
    acc += fgr[1] * W[129 * 256 + o];
    acc += fgr[2] * W[130 * 256 + o];
    y1[(size_t)g * 256 + o] = selu_f(acc);
}

__global__ __launch_bounds__(128) void mlp2_kernel(
        const float* __restrict__ y1, const float* __restrict__ W,
        const float* __restrict__ b, float* __restrict__ y2, int G) {
    int g = blockIdx.x;
    int o = threadIdx.x;
    if (g >= G) return;
    float acc = b[o];
    const float* in = y1 + (size_t)g * 256;
    #pragma unroll 8
    for (int k = 0; k < 256; ++k) acc += in[k] * W[k * 128 + o];
    y2[(size_t)g * 128 + o] = selu_f(acc);
}

__global__ void mlp3_kernel(const float* __restrict__ y2, const float* __restrict__ W,
                            const float* __restrict__ b, float* __restrict__ out, int G) {
    int g = blockIdx.x * blockDim.x + threadIdx.x;
    if (g >= G) return;
    const float* in = y2 + (size_t)g * 128;
    float acc = b[0];
    #pragma unroll 8
    for (int k = 0; k < 128; ++k) acc += in[k] * W[k];
    out[g] = acc;
}

extern "C" void kernel_launch(void* const* d_in, const int* in_sizes, int n_in,
                              void* d_out, int out_size, void* d_ws, size_t ws_size,
                              hipStream_t stream) {
    const float* feats_node  = (const float*)d_in[0];   // [N,64]
    const float* feats_graph = (const float*)d_in[1];   // [G,3]
    const int*   src         = (const int*)d_in[2];     // [E]
    const int*   dst         = (const int*)d_in[3];     // [E]
    const int*   node2graph  = (const int*)d_in[4];     // [N] (sorted)
    const float* W1 = (const float*)d_in[5];
    const float* b1 = (const float*)d_in[6];
    const float* W2 = (const float*)d_in[7];
    const float* b2 = (const float*)d_in[8];
    const float* W3 = (const float*)d_in[9];
    const float* b3 = (const float*)d_in[10];
    const float* L1w = (const float*)d_in[11];
    const float* L1b = (const float*)d_in[12];
    const float* L2w = (const float*)d_in[13];
    const float* L2b = (const float*)d_in[14];
    const float* L3w = (const float*)d_in[15];
    const float* L3b = (const float*)d_in[16];

    const int N = in_sizes[0] / 64;
    const int G = in_sizes[1] / 3;
    const int E = in_sizes[2];
    const int NB = (N + SCAN_B - 1) / SCAN_B;   // scan blocks

    // ---- workspace layout ----
    int* iws = (int*)d_ws;
    int* deg_out_i = iws;                 // N
    int* deg_in_i  = deg_out_i + N;       // N
    int* cursor    = deg_in_i + N;        // N
    int* row_start = cursor + N;          // N
    int* bsums     = row_start + N;       // NB (<=128)
    int* gstart    = bsums + 128;         // G+1 (padded to G+8)
    int* csr_src   = gstart + ((G + 8) & ~3); // E

    float* fws = (float*)(csr_src + E);
    float* norm_out = fws;                     // N
    float* norm_in  = norm_out + N;            // N
    float* csr_w    = norm_in + N;             // E
    float* agg      = csr_w + E;               // N*128
    float* xbuf     = agg + (size_t)N * 128;   // N*128
    float* gsum     = xbuf + (size_t)N * 128;  // G*128
    float* y1       = gsum + (size_t)G * 128;  // G*256
    float* y2       = y1 + (size_t)G * 256;    // G*128

    float* out = (float*)d_out;

    // ---- 1. degrees -> norms ----
    hipMemsetAsync(deg_out_i, 0, (size_t)3 * N * sizeof(int), stream);  // also zeroes cursor
    degree_kernel<<<(E + 255) / 256, 256, 0, stream>>>(src, dst, deg_out_i, deg_in_i, E);
    norm_kernel<<<(2 * N + 255) / 256, 256, 0, stream>>>(deg_out_i, norm_out, 2 * N);

    // ---- 2. CSR build (by dst) ----
    scan_block_sums<<<NB, 256, 0, stream>>>(deg_in_i, bsums, N);
    scan_bsums<<<1, 256, 0, stream>>>(bsums, NB);
    scan_apply<<<NB, 256, 0, stream>>>(deg_in_i, bsums, row_start, N);
    csr_fill_kernel<<<(E + 255) / 256, 256, 0, stream>>>(
        src, dst, norm_out, row_start, cursor, csr_src, csr_w, E);

    const int NPB = 32;
    const int gemm_grid = (N + NPB - 1) / NPB;

    // ---- 3. layer 1 (FIN=64) ----
    csr_agg_kernel<16, 64><<<(N + 15) / 16, 256, 0, stream>>>(
        feats_node, row_start, deg_in_i, csr_src, csr_w, agg, N);
    gemm_node_kernel<64, true><<<gemm_grid, 256, 0, stream>>>(
        agg, norm_in, W1, b1, xbuf, N, NPB);

    // ---- 4. layer 2 (FIN=128) ----
    csr_agg_kernel<32, 128><<<(N + 7) / 8, 256, 0, stream>>>(
        xbuf, row_start, deg_in_i, csr_src, csr_w, agg, N);
    gemm_node_kernel<128, true><<<gemm_grid, 256, 0, stream>>>(
        agg, norm_in, W2, b2, xbuf, N, NPB);

    // ---- 5. layer 3 (FIN=128, no selu) ----
    csr_agg_kernel<32, 128><<<(N + 7) / 8, 256, 0, stream>>>(
        xbuf, row_start, deg_in_i, csr_src, csr_w, agg, N);
    gemm_node_kernel<128, false><<<gemm_grid, 256, 0, stream>>>(
        agg, norm_in, W3, b3, xbuf, N, NPB);

    // ---- 6. readout (sorted node2graph -> contiguous ranges) ----
    graph_starts_kernel<<<(G + 1 + 255) / 256, 256, 0, stream>>>(node2graph, gstart, N, G);
    readout_kernel<<<G, 128, 0, stream>>>(xbuf, gstart, gsum, G);

    // ---- 7. MLP head ----
    mlp1_kernel<<<G, 256, 0, stream>>>(gsum, feats_graph, L1w, L1b, y1, G);
    mlp2_kernel<<<G, 128, 0, stream>>>(y1, L2w, L2b, y2, G);
    mlp3_kernel<<<(G + 255) / 256, 256, 0, stream>>>(y2, L3w, L3b, out, G);
}

// Round 3
// 884.349 us; speedup vs baseline: 8.6791x; 1.2551x over previous
//
#include <hip/hip_runtime.h>
#include <math.h>

#define SELU_ALPHA 1.6732632423543772f
#define SELU_SCALE 1.0507009873554805f

__device__ __forceinline__ float selu_f(float x) {
    return SELU_SCALE * (x > 0.f ? x : SELU_ALPHA * expm1f(x));
}

// ---- integer degree accumulation ----
__global__ void degree_kernel(const int* __restrict__ src, const int* __restrict__ dst,
                              int* __restrict__ dout, int* __restrict__ din, int E) {
    int e = blockIdx.x * blockDim.x + threadIdx.x;
    if (e >= E) return;
    atomicAdd(&dout[src[e]], 1);
    atomicAdd(&din[dst[e]], 1);
}

// norm[i] = 1/sqrt(max(deg,1)); processes 2N (out then in, contiguous)
__global__ void norm_kernel(const int* __restrict__ deg, float* __restrict__ norm, int n) {
    int i = blockIdx.x * blockDim.x + threadIdx.x;
    if (i >= n) return;
    norm[i] = 1.f / sqrtf(fmaxf((float)deg[i], 1.f));
}

// ---- exclusive scan of deg_in -> row_start (3 kernels) ----
#define SCAN_B 1024   // elements per block (256 thr x 4)

__global__ __launch_bounds__(256) void scan_block_sums(const int* __restrict__ in,
                                                       int* __restrict__ bsums, int n) {
    __shared__ int s[256];
    int b = blockIdx.x, t = threadIdx.x;
    int base = b * SCAN_B;
    int sum = 0;
    for (int i = t; i < SCAN_B; i += 256) {
        int idx = base + i;
        sum += (idx < n) ? in[idx] : 0;
    }
    s[t] = sum; __syncthreads();
    for (int off = 128; off > 0; off >>= 1) {
        if (t < off) s[t] += s[t + off];
        __syncthreads();
    }
    if (t == 0) bsums[b] = s[0];
}

__global__ __launch_bounds__(256) void scan_bsums(int* __restrict__ bsums, int nb) {
    __shared__ int s[256];
    __shared__ int carry_s;
    int t = threadIdx.x;
    if (t == 0) carry_s = 0;
    __syncthreads();
    for (int base = 0; base < nb; base += 256) {
        int idx = base + t;
        int v = (idx < nb) ? bsums[idx] : 0;
        s[t] = v; __syncthreads();
        for (int off = 1; off < 256; off <<= 1) {
            int x = (t >= off) ? s[t - off] : 0;
            __syncthreads();
            s[t] += x;
            __syncthreads();
        }
        int incl = s[t];
        int excl = incl - v;
        int c = carry_s;
        __syncthreads();
        if (idx < nb) bsums[idx] = c + excl;
        if (t == 255) carry_s = c + incl;
        __syncthreads();
    }
}

__global__ __launch_bounds__(256) void scan_apply(const int* __restrict__ in,
                                                  const int* __restrict__ boffs,
                                                  int* __restrict__ out, int n) {
    __shared__ int s[256];
    int b = blockIdx.x, t = threadIdx.x;
    int idx0 = b * SCAN_B + t * 4;
    int v[4]; int tsum = 0;
    #pragma unroll
    for (int k = 0; k < 4; ++k) {
        int idx = idx0 + k;
        v[k] = (idx < n) ? in[idx] : 0;
        tsum += v[k];
    }
    s[t] = tsum; __syncthreads();
    for (int off = 1; off < 256; off <<= 1) {
        int x = (t >= off) ? s[t - off] : 0;
        __syncthreads();
        s[t] += x;
        __syncthreads();
    }
    int run = s[t] - tsum + boffs[b];
    #pragma unroll
    for (int k = 0; k < 4; ++k) {
        int idx = idx0 + k;
        if (idx < n) out[idx] = run;
        run += v[k];
    }
}

// ---- CSR fill ----
__global__ void csr_fill_kernel(const int* __restrict__ src, const int* __restrict__ dst,
                                const float* __restrict__ norm_out,
                                const int* __restrict__ row_start, int* __restrict__ cursor,
                                int* __restrict__ csr_src, float* __restrict__ csr_w, int E) {
    int e = blockIdx.x * blockDim.x + threadIdx.x;
    if (e >= E) return;
    int d = dst[e], s = src[e];
    int pos = row_start[d] + atomicAdd(&cursor[d], 1);
    csr_src[pos] = s;
    csr_w[pos] = norm_out[s];
}

// ---- gather-aggregate: agg[n] = sum_{e in CSR[n]} csr_w[e] * x[csr_src[e]] ----
template<int TPG, int FIN>
__global__ __launch_bounds__(256) void csr_agg_kernel(
        const float* __restrict__ x, const int* __restrict__ row_start,
        const int* __restrict__ deg, const int* __restrict__ csr_src,
        const float* __restrict__ csr_w, float* __restrict__ agg, int N) {
    const int GPB = 256 / TPG;
    int g = threadIdx.x / TPG;
    int j = threadIdx.x % TPG;
    int n = blockIdx.x * GPB + g;
    if (n >= N) return;
    int beg = row_start[n];
    int end = beg + deg[n];
    float4 acc = make_float4(0.f, 0.f, 0.f, 0.f);
    for (int e = beg; e < end; ++e) {
        int s = csr_src[e];
        float w = csr_w[e];
        float4 v = reinterpret_cast<const float4*>(x + (size_t)s * FIN)[j];
        acc.x += v.x * w; acc.y += v.y * w; acc.z += v.z * w; acc.w += v.w * w;
    }
    reinterpret_cast<float4*>(agg + (size_t)n * FIN)[j] = acc;
}

// ---- per-node dense GEMM: out[n] = act((agg[n]*norm_in[n]) @ W + b), FOUT=128 ----
// Persistent blocks. Tile = 32 nodes x 128 outputs. Thread = 4 nodes x 4 outputs.
// sW[k][128] (64KB @FIN=128), sA[node][FIN] (16KB). A-reads broadcast (free),
// W-reads lane-consecutive b128 (conflict-free). VALU-bound inner loop.
template<int FIN, bool SELU>
__global__ __launch_bounds__(256, 2) void gemm_node_kernel(
        const float* __restrict__ agg, const float* __restrict__ norm_in,
        const float* __restrict__ W, const float* __restrict__ b,
        float* __restrict__ out, int N, int n_tiles) {
    __shared__ float sW[FIN * 128];
    __shared__ float sA[32 * FIN];
    const int tid = threadIdx.x;
    const int o4 = tid & 31;    // output quad: outputs 4*o4 .. 4*o4+3
    const int ng = tid >> 5;    // node group: nodes ng*4 .. ng*4+3 within tile

    // stage W once (float4)
    {
        const float4* W4 = reinterpret_cast<const float4*>(W);
        float4* sW4 = reinterpret_cast<float4*>(sW);
        for (int i = tid; i < FIN * 32; i += 256) sW4[i] = W4[i];
    }
    const float4 bias4 = reinterpret_cast<const float4*>(b)[o4];
    __syncthreads();

    const float4* sA4 = reinterpret_cast<const float4*>(sA);
    const float4* sW4 = reinterpret_cast<const float4*>(sW);

    for (int tile = blockIdx.x; tile < n_tiles; tile += gridDim.x) {
        const int n0 = tile * 32;
        // stage A (coalesced float4), scaled by norm_in
        {
            float4* dA = reinterpret_cast<float4*>(sA);
            for (int i = tid; i < 8 * FIN; i += 256) {
                int node = i / (FIN / 4);
                int kq = i % (FIN / 4);
                int n = n0 + node;
                float4 v = make_float4(0.f, 0.f, 0.f, 0.f);
                if (n < N) {
                    v = reinterpret_cast<const float4*>(agg + (size_t)n * FIN)[kq];
                    float s = norm_in[n];
                    v.x *= s; v.y *= s; v.z *= s; v.w *= s;
                }
                dA[i] = v;
            }
        }
        __syncthreads();

        float4 acc[4];
        #pragma unroll
        for (int i = 0; i < 4; ++i) acc[i] = bias4;

        #pragma unroll 4
        for (int k0 = 0; k0 < FIN; k0 += 4) {
            float4 a[4], w[4];
            #pragma unroll
            for (int i = 0; i < 4; ++i)
                a[i] = sA4[(ng * 4 + i) * (FIN / 4) + (k0 >> 2)];
            #pragma unroll
            for (int j = 0; j < 4; ++j)
                w[j] = sW4[(k0 + j) * 32 + o4];
            #pragma unroll
            for (int i = 0; i < 4; ++i) {
                acc[i].x += a[i].x * w[0].x + a[i].y * w[1].x + a[i].z * w[2].x + a[i].w * w[3].x;
                acc[i].y += a[i].x * w[0].y + a[i].y * w[1].y + a[i].z * w[2].y + a[i].w * w[3].y;
                acc[i].z += a[i].x * w[0].z + a[i].y * w[1].z + a[i].z * w[2].z + a[i].w * w[3].z;
                acc[i].w += a[i].x * w[0].w + a[i].y * w[1].w + a[i].z * w[2].w + a[i].w * w[3].w;
            }
        }

        #pragma unroll
        for (int i = 0; i < 4; ++i) {
            int n = n0 + ng * 4 + i;
            if (n < N) {
                float4 r = acc[i];
                if (SELU) {
                    r.x = selu_f(r.x); r.y = selu_f(r.y);
                    r.z = selu_f(r.z); r.w = selu_f(r.w);
                }
                reinterpret_cast<float4*>(out + (size_t)n * 128)[o4] = r;
            }
        }
        __syncthreads();
    }
}

// ---- graph range starts via binary search (node2graph is sorted) ----
__global__ void graph_starts_kernel(const int* __restrict__ n2g, int* __restrict__ gstart,
                                    int N, int G) {
    int g = blockIdx.x * blockDim.x + threadIdx.x;
    if (g > G) return;
    int lo = 0, hi = N;
    while (lo < hi) {
        int mid = (lo + hi) >> 1;
        if (n2g[mid] < g) lo = mid + 1; else hi = mid;
    }
    gstart[g] = lo;
}

// ---- readout ----
__global__ __launch_bounds__(128) void readout_kernel(
        const float* __restrict__ y, const int* __restrict__ gstart,
        float* __restrict__ gsum, int G) {
    int g = blockIdx.x;
    int o = threadIdx.x;
    if (g >= G) return;
    int beg = gstart[g], end = gstart[g + 1];
    float acc = 0.f;
    for (int n = beg; n < end; ++n)
        acc += y[(size_t)n * 128 + o];
    gsum[(size_t)g * 128 + o] = acc;
}

// ---- MLP layers ----
__global__ __launch_bounds__(256) void mlp1_kernel(
        const float* __restrict__ gsum, const float* __restrict__ fg,
        const float* __restrict__ W, const float* __restrict__ b,
        float* __restrict__ y1, int G) {
    int g = blockIdx.x;
    int o = threadIdx.x;
    if (g >= G) return;
    float acc = b[o];
    const float* in = gsum + (size_t)g * 128;
    #pragma unroll 8
    for (int k = 0; k < 128; ++k) acc += in[k] * W[k * 256 + o];
    const float* fgr = fg + (size_t)g * 3;
    acc += fgr[0] * W[128 * 256 + o];
    acc += fgr[1] * W[129 * 256 + o];
    acc += fgr[2] * W[130 * 256 + o];
    y1[(size_t)g * 256 + o] = selu_f(acc);
}

__global__ __launch_bounds__(128) void mlp2_kernel(
        const float* __restrict__ y1, const float* __restrict__ W,
        const float* __restrict__ b, float* __restrict__ y2, int G) {
    int g = blockIdx.x;
    int o = threadIdx.x;
    if (g >= G) return;
    float acc = b[o];
    const float* in = y1 + (size_t)g * 256;
    #pragma unroll 8
    for (int k = 0; k < 256; ++k) acc += in[k] * W[k * 128 + o];
    y2[(size_t)g * 128 + o] = selu_f(acc);
}

__global__ void mlp3_kernel(const float* __restrict__ y2, const float* __restrict__ W,
                            const float* __restrict__ b, float* __restrict__ out, int G) {
    int g = blockIdx.x * blockDim.x + threadIdx.x;
    if (g >= G) return;
    const float* in = y2 + (size_t)g * 128;
    float acc = b[0];
    #pragma unroll 8
    for (int k = 0; k < 128; ++k) acc += in[k] * W[k];
    out[g] = acc;
}

extern "C" void kernel_launch(void* const* d_in, const int* in_sizes, int n_in,
                              void* d_out, int out_size, void* d_ws, size_t ws_size,
                              hipStream_t stream) {
    const float* feats_node  = (const float*)d_in[0];   // [N,64]
    const float* feats_graph = (const float*)d_in[1];   // [G,3]
    const int*   src         = (const int*)d_in[2];     // [E]
    const int*   dst         = (const int*)d_in[3];     // [E]
    const int*   node2graph  = (const int*)d_in[4];     // [N] (sorted)
    const float* W1 = (const float*)d_in[5];
    const float* b1 = (const float*)d_in[6];
    const float* W2 = (const float*)d_in[7];
    const float* b2 = (const float*)d_in[8];
    const float* W3 = (const float*)d_in[9];
    const float* b3 = (const float*)d_in[10];
    const float* L1w = (const float*)d_in[11];
    const float* L1b = (const float*)d_in[12];
    const float* L2w = (const float*)d_in[13];
    const float* L2b = (const float*)d_in[14];
    const float* L3w = (const float*)d_in[15];
    const float* L3b = (const float*)d_in[16];

    const int N = in_sizes[0] / 64;
    const int G = in_sizes[1] / 3;
    const int E = in_sizes[2];
    const int NB = (N + SCAN_B - 1) / SCAN_B;

    // ---- workspace layout ----
    int* iws = (int*)d_ws;
    int* deg_out_i = iws;                 // N
    int* deg_in_i  = deg_out_i + N;       // N
    int* cursor    = deg_in_i + N;        // N
    int* row_start = cursor + N;          // N
    int* bsums     = row_start + N;       // NB (<=128)
    int* gstart    = bsums + 128;         // G+1 (padded)
    int* csr_src   = gstart + ((G + 8) & ~3); // E

    float* fws = (float*)(csr_src + E);
    float* norm_out = fws;                     // N
    float* norm_in  = norm_out + N;            // N
    float* csr_w    = norm_in + N;             // E
    float* agg      = csr_w + E;               // N*128
    float* xbuf     = agg + (size_t)N * 128;   // N*128
    float* gsum     = xbuf + (size_t)N * 128;  // G*128
    float* y1       = gsum + (size_t)G * 128;  // G*256
    float* y2       = y1 + (size_t)G * 256;    // G*128

    float* out = (float*)d_out;

    // ---- 1. degrees -> norms ----
    hipMemsetAsync(deg_out_i, 0, (size_t)3 * N * sizeof(int), stream);  // also zeroes cursor
    degree_kernel<<<(E + 255) / 256, 256, 0, stream>>>(src, dst, deg_out_i, deg_in_i, E);
    norm_kernel<<<(2 * N + 255) / 256, 256, 0, stream>>>(deg_out_i, norm_out, 2 * N);

    // ---- 2. CSR build (by dst) ----
    scan_block_sums<<<NB, 256, 0, stream>>>(deg_in_i, bsums, N);
    scan_bsums<<<1, 256, 0, stream>>>(bsums, NB);
    scan_apply<<<NB, 256, 0, stream>>>(deg_in_i, bsums, row_start, N);
    csr_fill_kernel<<<(E + 255) / 256, 256, 0, stream>>>(
        src, dst, norm_out, row_start, cursor, csr_src, csr_w, E);

    const int n_tiles = (N + 31) / 32;

    // ---- 3. layer 1 (FIN=64) ----
    csr_agg_kernel<16, 64><<<(N + 15) / 16, 256, 0, stream>>>(
        feats_node, row_start, deg_in_i, csr_src, csr_w, agg, N);
    gemm_node_kernel<64, true><<<1024, 256, 0, stream>>>(
        agg, norm_in, W1, b1, xbuf, N, n_tiles);

    // ---- 4. layer 2 (FIN=128) ----
    csr_agg_kernel<32, 128><<<(N + 7) / 8, 256, 0, stream>>>(
        xbuf, row_start, deg_in_i, csr_src, csr_w, agg, N);
    gemm_node_kernel<128, true><<<512, 256, 0, stream>>>(
        agg, norm_in, W2, b2, xbuf, N, n_tiles);

    // ---- 5. layer 3 (FIN=128, no selu) ----
    csr_agg_kernel<32, 128><<<(N + 7) / 8, 256, 0, stream>>>(
        xbuf, row_start, deg_in_i, csr_src, csr_w, agg, N);
    gemm_node_kernel<128, false><<<512, 256, 0, stream>>>(
        agg, norm_in, W3, b3, xbuf, N, n_tiles);

    // ---- 6. readout ----
    graph_starts_kernel<<<(G + 1 + 255) / 256, 256, 0, stream>>>(node2graph, gstart, N, G);
    readout_kernel<<<G, 128, 0, stream>>>(xbuf, gstart, gsum, G);

    // ---- 7. MLP head ----
    mlp1_kernel<<<G, 256, 0, stream>>>(gsum, feats_graph, L1w, L1b, y1, G);
    mlp2_kernel<<<G, 128, 0, stream>>>(y1, L2w, L2b, y2, G);
    mlp3_kernel<<<(G + 255) / 256, 256, 0, stream>>>(y2, L3w, L3b, out, G);
}

// Round 4
// 629.180 us; speedup vs baseline: 12.1990x; 1.4056x over previous
//
#include <hip/hip_runtime.h>
#include <math.h>

#define SELU_ALPHA 1.6732632423543772f
#define SELU_SCALE 1.0507009873554805f

typedef __attribute__((ext_vector_type(8))) short bf16x8;
typedef __attribute__((ext_vector_type(4))) float f32x4;

__device__ __forceinline__ float selu_f(float x) {
    return SELU_SCALE * (x > 0.f ? x : SELU_ALPHA * expm1f(x));
}

__device__ __forceinline__ float bf2f(unsigned short u) {
    return __uint_as_float(((unsigned)u) << 16);
}
__device__ __forceinline__ unsigned short f2bf(float f) {
    unsigned u = __float_as_uint(f);
    unsigned r = (u + 0x7fffu + ((u >> 16) & 1u)) >> 16;
    return (unsigned short)r;
}

// ---- integer degree accumulation ----
__global__ void degree_kernel(const int* __restrict__ src, const int* __restrict__ dst,
                              int* __restrict__ dout, int* __restrict__ din, int E) {
    int e = blockIdx.x * blockDim.x + threadIdx.x;
    if (e >= E) return;
    atomicAdd(&dout[src[e]], 1);
    atomicAdd(&din[dst[e]], 1);
}

__global__ void norm_kernel(const int* __restrict__ deg, float* __restrict__ norm, int n) {
    int i = blockIdx.x * blockDim.x + threadIdx.x;
    if (i >= n) return;
    norm[i] = 1.f / sqrtf(fmaxf((float)deg[i], 1.f));
}

// ---- exclusive scan of deg_in -> row_start ----
#define SCAN_B 1024

__global__ __launch_bounds__(256) void scan_block_sums(const int* __restrict__ in,
                                                       int* __restrict__ bsums, int n) {
    __shared__ int s[256];
    int b = blockIdx.x, t = threadIdx.x;
    int base = b * SCAN_B;
    int sum = 0;
    for (int i = t; i < SCAN_B; i += 256) {
        int idx = base + i;
        sum += (idx < n) ? in[idx] : 0;
    }
    s[t] = sum; __syncthreads();
    for (int off = 128; off > 0; off >>= 1) {
        if (t < off) s[t] += s[t + off];
        __syncthreads();
    }
    if (t == 0) bsums[b] = s[0];
}

__global__ __launch_bounds__(256) void scan_bsums(int* __restrict__ bsums, int nb) {
    __shared__ int s[256];
    __shared__ int carry_s;
    int t = threadIdx.x;
    if (t == 0) carry_s = 0;
    __syncthreads();
    for (int base = 0; base < nb; base += 256) {
        int idx = base + t;
        int v = (idx < nb) ? bsums[idx] : 0;
        s[t] = v; __syncthreads();
        for (int off = 1; off < 256; off <<= 1) {
            int x = (t >= off) ? s[t - off] : 0;
            __syncthreads();
            s[t] += x;
            __syncthreads();
        }
        int incl = s[t];
        int excl = incl - v;
        int c = carry_s;
        __syncthreads();
        if (idx < nb) bsums[idx] = c + excl;
        if (t == 255) carry_s = c + incl;
        __syncthreads();
    }
}

__global__ __launch_bounds__(256) void scan_apply(const int* __restrict__ in,
                                                  const int* __restrict__ boffs,
                                                  int* __restrict__ out, int n) {
    __shared__ int s[256];
    int b = blockIdx.x, t = threadIdx.x;
    int idx0 = b * SCAN_B + t * 4;
    int v[4]; int tsum = 0;
    #pragma unroll
    for (int k = 0; k < 4; ++k) {
        int idx = idx0 + k;
        v[k] = (idx < n) ? in[idx] : 0;
        tsum += v[k];
    }
    s[t] = tsum; __syncthreads();
    for (int off = 1; off < 256; off <<= 1) {
        int x = (t >= off) ? s[t - off] : 0;
        __syncthreads();
        s[t] += x;
        __syncthreads();
    }
    int run = s[t] - tsum + boffs[b];
    #pragma unroll
    for (int k = 0; k < 4; ++k) {
        int idx = idx0 + k;
        if (idx < n) out[idx] = run;
        run += v[k];
    }
}

// ---- CSR fill ----
__global__ void csr_fill_kernel(const int* __restrict__ src, const int* __restrict__ dst,
                                const float* __restrict__ norm_out,
                                const int* __restrict__ row_start, int* __restrict__ cursor,
                                int* __restrict__ csr_src, float* __restrict__ csr_w, int E) {
    int e = blockIdx.x * blockDim.x + threadIdx.x;
    if (e >= E) return;
    int d = dst[e], s = src[e];
    int pos = row_start[d] + atomicAdd(&cursor[d], 1);
    csr_src[pos] = s;
    csr_w[pos] = norm_out[s];
}

// ---- prep: fp32 -> bf16 elementwise (vectorized x4) ----
__global__ void cvt_bf16_kernel(const float* __restrict__ in, unsigned short* __restrict__ out,
                                int n4) {
    int i = blockIdx.x * blockDim.x + threadIdx.x;
    if (i >= n4) return;
    float4 v = reinterpret_cast<const float4*>(in)[i];
    unsigned short o[4] = { f2bf(v.x), f2bf(v.y), f2bf(v.z), f2bf(v.w) };
    reinterpret_cast<uint2*>(out)[i] = *reinterpret_cast<uint2*>(o);
}

// ---- prep: W [K][128] fp32 -> Wt [128][K] bf16 ----
__global__ void wt_transpose_kernel(const float* __restrict__ W, unsigned short* __restrict__ Wt,
                                    int K) {
    int i = blockIdx.x * blockDim.x + threadIdx.x;  // i = col*K + k
    if (i >= 128 * K) return;
    int col = i / K, k = i % K;
    Wt[i] = f2bf(W[k * 128 + col]);
}

// ---- gather-aggregate (bf16 x): agg16[n] = f2bf(norm_in[n] * sum_e w_e * x[src_e]) ----
template<int TPG, int FIN>   // TPG = FIN/8
__global__ __launch_bounds__(256) void csr_agg_kernel(
        const unsigned short* __restrict__ x, const int* __restrict__ row_start,
        const int* __restrict__ deg, const int* __restrict__ csr_src,
        const float* __restrict__ csr_w, const float* __restrict__ norm_in,
        unsigned short* __restrict__ agg, int N) {
    const int GPB = 256 / TPG;
    int g = threadIdx.x / TPG;
    int j = threadIdx.x % TPG;
    int n = blockIdx.x * GPB + g;
    if (n >= N) return;
    int beg = row_start[n];
    int end = beg + deg[n];
    float acc[8] = {0.f, 0.f, 0.f, 0.f, 0.f, 0.f, 0.f, 0.f};
    for (int e = beg; e < end; ++e) {
        int s = csr_src[e];
        float w = csr_w[e];
        float4 raw = *reinterpret_cast<const float4*>(&x[(size_t)s * FIN + j * 8]);
        const unsigned short* u = reinterpret_cast<const unsigned short*>(&raw);
        #pragma unroll
        for (int t = 0; t < 8; ++t)
            acc[t] += w * bf2f(u[t]);
    }
    float nin = norm_in[n];
    unsigned short ov[8];
    #pragma unroll
    for (int t = 0; t < 8; ++t) ov[t] = f2bf(acc[t] * nin);
    *reinterpret_cast<float4*>(&agg[(size_t)n * FIN + j * 8]) = *reinterpret_cast<float4*>(ov);
}

// ---- MFMA node GEMM: out[n] = act(agg16[n] @ Wt^T + b) ----
// Block: 256 thr = 4 waves, tile 128 nodes x 128 outs. Wave: 64x64 (4x4 frags of 16x16x32).
// sA/sW row-padded +8 bf16 -> 2-way-max bank aliasing on b128 frag reads.
template<int FIN, bool SELU, bool OUT_BF16>
__global__ __launch_bounds__(256, 2) void gemm_mfma_kernel(
        const unsigned short* __restrict__ agg16,  // [N][FIN] bf16 (norm-scaled)
        const unsigned short* __restrict__ Wt,     // [128][FIN] bf16
        const float* __restrict__ b,               // [128]
        void* __restrict__ out,                    // [N][128] bf16 or fp32
        int N) {
    const int PAD = 8;
    const int LDA = FIN + PAD;
    __shared__ unsigned short sA[128 * LDA];
    __shared__ unsigned short sW[128 * LDA];
    const int tid = threadIdx.x;
    const int wave = tid >> 6, lane = tid & 63;
    const int wr = (wave >> 1) * 64;   // wave row offset in tile
    const int wc = (wave & 1) * 64;    // wave col offset
    const int n0 = blockIdx.x * 128;
    const int CH = FIN / 8;            // 16B chunks per row

    // stage Wt (bf16, coalesced 16B)
    for (int i = tid; i < 128 * CH; i += 256) {
        int col = i / CH, kc = i % CH;
        *reinterpret_cast<float4*>(&sW[col * LDA + kc * 8]) =
            *reinterpret_cast<const float4*>(&Wt[col * FIN + kc * 8]);
    }
    // stage A (bf16, coalesced 16B; zero-pad tail nodes)
    for (int i = tid; i < 128 * CH; i += 256) {
        int node = i / CH, kc = i % CH;
        int n = n0 + node;
        float4 v = make_float4(0.f, 0.f, 0.f, 0.f);
        if (n < N)
            v = *reinterpret_cast<const float4*>(&agg16[(size_t)n * FIN + kc * 8]);
        *reinterpret_cast<float4*>(&sA[node * LDA + kc * 8]) = v;
    }
    __syncthreads();

    const int l16 = lane & 15;
    const int lk = (lane >> 4) * 8;
    f32x4 acc[4][4];
    #pragma unroll
    for (int mi = 0; mi < 4; ++mi)
        #pragma unroll
        for (int ci = 0; ci < 4; ++ci)
            acc[mi][ci] = (f32x4){0.f, 0.f, 0.f, 0.f};

    #pragma unroll
    for (int k0 = 0; k0 < FIN; k0 += 32) {
        bf16x8 a[4], w[4];
        #pragma unroll
        for (int mi = 0; mi < 4; ++mi)
            a[mi] = *reinterpret_cast<const bf16x8*>(&sA[(wr + mi * 16 + l16) * LDA + k0 + lk]);
        #pragma unroll
        for (int ci = 0; ci < 4; ++ci)
            w[ci] = *reinterpret_cast<const bf16x8*>(&sW[(wc + ci * 16 + l16) * LDA + k0 + lk]);
        #pragma unroll
        for (int mi = 0; mi < 4; ++mi)
            #pragma unroll
            for (int ci = 0; ci < 4; ++ci)
                acc[mi][ci] = __builtin_amdgcn_mfma_f32_16x16x32_bf16(
                    a[mi], w[ci], acc[mi][ci], 0, 0, 0);
    }

    // epilogue: D frag (m89): col = lane&15, row = (lane>>4)*4 + r
    const int rbase = (lane >> 4) * 4;
    #pragma unroll
    for (int ci = 0; ci < 4; ++ci) {
        int col = wc + ci * 16 + l16;
        float bias = b[col];
        #pragma unroll
        for (int mi = 0; mi < 4; ++mi) {
            #pragma unroll
            for (int r = 0; r < 4; ++r) {
                int n = n0 + wr + mi * 16 + rbase + r;
                if (n < N) {
                    float v = acc[mi][ci][r] + bias;
                    if (SELU) v = selu_f(v);
                    if (OUT_BF16)
                        ((unsigned short*)out)[(size_t)n * 128 + col] = f2bf(v);
                    else
                        ((float*)out)[(size_t)n * 128 + col] = v;
                }
            }
        }
    }
}

// ---- graph range starts (node2graph sorted) ----
__global__ void graph_starts_kernel(const int* __restrict__ n2g, int* __restrict__ gstart,
                                    int N, int G) {
    int g = blockIdx.x * blockDim.x + threadIdx.x;
    if (g > G) return;
    int lo = 0, hi = N;
    while (lo < hi) {
        int mid = (lo + hi) >> 1;
        if (n2g[mid] < g) lo = mid + 1; else hi = mid;
    }
    gstart[g] = lo;
}

// ---- readout from bf16 y ----
__global__ __launch_bounds__(128) void readout_kernel(
        const unsigned short* __restrict__ y, const int* __restrict__ gstart,
        float* __restrict__ gsum, int G) {
    int g = blockIdx.x;
    int o = threadIdx.x;
    if (g >= G) return;
    int beg = gstart[g], end = gstart[g + 1];
    float acc = 0.f;
    for (int n = beg; n < end; ++n)
        acc += bf2f(y[(size_t)n * 128 + o]);
    gsum[(size_t)g * 128 + o] = acc;
}

// ---- MLP head (fp32) ----
__global__ __launch_bounds__(256) void mlp1_kernel(
        const float* __restrict__ gsum, const float* __restrict__ fg,
        const float* __restrict__ W, const float* __restrict__ b,
        float* __restrict__ y1, int G) {
    int g = blockIdx.x;
    int o = threadIdx.x;
    if (g >= G) return;
    float acc = b[o];
    const float* in = gsum + (size_t)g * 128;
    #pragma unroll 8
    for (int k = 0; k < 128; ++k) acc += in[k] * W[k * 256 + o];
    const float* fgr = fg + (size_t)g * 3;
    acc += fgr[0] * W[128 * 256 + o];
    acc += fgr[1] * W[129 * 256 + o];
    acc += fgr[2] * W[130 * 256 + o];
    y1[(size_t)g * 256 + o] = selu_f(acc);
}

__global__ __launch_bounds__(128) void mlp2_kernel(
        const float* __restrict__ y1, const float* __restrict__ W,
        const float* __restrict__ b, float* __restrict__ y2, int G) {
    int g = blockIdx.x;
    int o = threadIdx.x;
    if (g >= G) return;
    float acc = b[o];
    const float* in = y1 + (size_t)g * 256;
    #pragma unroll 8
    for (int k = 0; k < 256; ++k) acc += in[k] * W[k * 128 + o];
    y2[(size_t)g * 128 + o] = selu_f(acc);
}

__global__ void mlp3_kernel(const float* __restrict__ y2, const float* __restrict__ W,
                            const float* __restrict__ b, float* __restrict__ out, int G) {
    int g = blockIdx.x * blockDim.x + threadIdx.x;
    if (g >= G) return;
    const float* in = y2 + (size_t)g * 128;
    float acc = b[0];
    #pragma unroll 8
    for (int k = 0; k < 128; ++k) acc += in[k] * W[k];
    out[g] = acc;
}

extern "C" void kernel_launch(void* const* d_in, const int* in_sizes, int n_in,
                              void* d_out, int out_size, void* d_ws, size_t ws_size,
                              hipStream_t stream) {
    const float* feats_node  = (const float*)d_in[0];
    const float* feats_graph = (const float*)d_in[1];
    const int*   src         = (const int*)d_in[2];
    const int*   dst         = (const int*)d_in[3];
    const int*   node2graph  = (const int*)d_in[4];
    const float* W1 = (const float*)d_in[5];
    const float* b1 = (const float*)d_in[6];
    const float* W2 = (const float*)d_in[7];
    const float* b2 = (const float*)d_in[8];
    const float* W3 = (const float*)d_in[9];
    const float* b3 = (const float*)d_in[10];
    const float* L1w = (const float*)d_in[11];
    const float* L1b = (const float*)d_in[12];
    const float* L2w = (const float*)d_in[13];
    const float* L2b = (const float*)d_in[14];
    const float* L3w = (const float*)d_in[15];
    const float* L3b = (const float*)d_in[16];

    const int N = in_sizes[0] / 64;
    const int G = in_sizes[1] / 3;
    const int E = in_sizes[2];
    const int NB = (N + SCAN_B - 1) / SCAN_B;

    // ---- workspace layout ----
    int* iws = (int*)d_ws;
    int* deg_out_i = iws;                 // N
    int* deg_in_i  = deg_out_i + N;       // N
    int* cursor    = deg_in_i + N;        // N
    int* row_start = cursor + N;          // N
    int* bsums     = row_start + N;       // 128
    int* gstart    = bsums + 128;         // G+8
    int* csr_src   = gstart + (G + 8);    // E

    float* norm_out = (float*)(csr_src + E);   // N
    float* norm_in  = norm_out + N;            // N
    float* csr_w    = norm_in + N;             // E

    unsigned short* feats16 = (unsigned short*)(csr_w + E);       // N*64
    unsigned short* x16     = feats16 + (size_t)N * 64;           // N*128
    unsigned short* agg16   = x16 + (size_t)N * 128;              // N*128
    unsigned short* y16     = agg16 + (size_t)N * 128;            // N*128
    unsigned short* Wt1     = y16 + (size_t)N * 128;              // 128*64
    unsigned short* Wt2     = Wt1 + 128 * 64;                     // 128*128
    unsigned short* Wt3     = Wt2 + 128 * 128;                    // 128*128

    float* gsum = (float*)(Wt3 + 128 * 128);   // G*128
    float* y1   = gsum + (size_t)G * 128;      // G*256
    float* y2   = y1 + (size_t)G * 256;        // G*128

    float* out = (float*)d_out;

    // ---- 0. prep: bf16 conversions + W transposes ----
    cvt_bf16_kernel<<<(N * 16 + 255) / 256, 256, 0, stream>>>(feats_node, feats16, N * 16);
    wt_transpose_kernel<<<(128 * 64 + 255) / 256, 256, 0, stream>>>(W1, Wt1, 64);
    wt_transpose_kernel<<<(128 * 128 + 255) / 256, 256, 0, stream>>>(W2, Wt2, 128);
    wt_transpose_kernel<<<(128 * 128 + 255) / 256, 256, 0, stream>>>(W3, Wt3, 128);

    // ---- 1. degrees -> norms ----
    hipMemsetAsync(deg_out_i, 0, (size_t)3 * N * sizeof(int), stream);  // also zeroes cursor
    degree_kernel<<<(E + 255) / 256, 256, 0, stream>>>(src, dst, deg_out_i, deg_in_i, E);
    norm_kernel<<<(2 * N + 255) / 256, 256, 0, stream>>>(deg_out_i, norm_out, 2 * N);

    // ---- 2. CSR build (by dst) ----
    scan_block_sums<<<NB, 256, 0, stream>>>(deg_in_i, bsums, N);
    scan_bsums<<<1, 256, 0, stream>>>(bsums, NB);
    scan_apply<<<NB, 256, 0, stream>>>(deg_in_i, bsums, row_start, N);
    csr_fill_kernel<<<(E + 255) / 256, 256, 0, stream>>>(
        src, dst, norm_out, row_start, cursor, csr_src, csr_w, E);

    const int gemm_grid = (N + 127) / 128;

    // ---- 3. layer 1 (FIN=64) ----
    csr_agg_kernel<8, 64><<<(N + 31) / 32, 256, 0, stream>>>(
        feats16, row_start, deg_in_i, csr_src, csr_w, norm_in, agg16, N);
    gemm_mfma_kernel<64, true, true><<<gemm_grid, 256, 0, stream>>>(
        agg16, Wt1, b1, x16, N);

    // ---- 4. layer 2 (FIN=128) ----
    csr_agg_kernel<16, 128><<<(N + 15) / 16, 256, 0, stream>>>(
        x16, row_start, deg_in_i, csr_src, csr_w, norm_in, agg16, N);
    gemm_mfma_kernel<128, true, true><<<gemm_grid, 256, 0, stream>>>(
        agg16, Wt2, b2, x16, N);

    // ---- 5. layer 3 (FIN=128, no selu, bf16 out for readout) ----
    csr_agg_kernel<16, 128><<<(N + 15) / 16, 256, 0, stream>>>(
        x16, row_start, deg_in_i, csr_src, csr_w, norm_in, agg16, N);
    gemm_mfma_kernel<128, false, true><<<gemm_grid, 256, 0, stream>>>(
        agg16, Wt3, b3, y16, N);

    // ---- 6. readout ----
    graph_starts_kernel<<<(G + 1 + 255) / 256, 256, 0, stream>>>(node2graph, gstart, N, G);
    readout_kernel<<<G, 128, 0, stream>>>(y16, gstart, gsum, G);

    // ---- 7. MLP head ----
    mlp1_kernel<<<G, 256, 0, stream>>>(gsum, feats_graph, L1w, L1b, y1, G);
    mlp2_kernel<<<G, 128, 0, stream>>>(y1, L2w, L2b, y2, G);
    mlp3_kernel<<<(G + 255) / 256, 256, 0, stream>>>(y2, L3w, L3b, out, G);
}

// Round 5
// 519.601 us; speedup vs baseline: 14.7716x; 1.2109x over previous
//
#include <hip/hip_runtime.h>
#include <math.h>

#define SELU_ALPHA 1.6732632423543772f
#define SELU_SCALE 1.0507009873554805f

#define NBLK 512          // partition blocks (E divides exactly: 512*3125)
#define MAXBKT 512        // static LDS sizing; actual NBKT = ceil(N/256)

typedef __attribute__((ext_vector_type(8))) short bf16x8;
typedef __attribute__((ext_vector_type(4))) float f32x4;

__device__ __forceinline__ float selu_f(float x) {
    return SELU_SCALE * (x > 0.f ? x : SELU_ALPHA * expm1f(x));
}

__device__ __forceinline__ float bf2f(unsigned short u) {
    return __uint_as_float(((unsigned)u) << 16);
}
__device__ __forceinline__ unsigned short f2bf(float f) {
    unsigned u = __float_as_uint(f);
    unsigned r = (u + 0x7fffu + ((u >> 16) & 1u)) >> 16;
    return (unsigned short)r;
}

__global__ void norm_kernel(const int* __restrict__ deg, float* __restrict__ norm, int n) {
    int i = blockIdx.x * blockDim.x + threadIdx.x;
    if (i >= n) return;
    norm[i] = 1.f / sqrtf(fmaxf((float)deg[i], 1.f));
}

// ---- exclusive scan (3 kernels), in-place safe ----
#define SCAN_B 1024

__global__ __launch_bounds__(256) void scan_block_sums(const int* __restrict__ in,
                                                       int* __restrict__ bsums, int n) {
    __shared__ int s[256];
    int b = blockIdx.x, t = threadIdx.x;
    int base = b * SCAN_B;
    int sum = 0;
    for (int i = t; i < SCAN_B; i += 256) {
        int idx = base + i;
        sum += (idx < n) ? in[idx] : 0;
    }
    s[t] = sum; __syncthreads();
    for (int off = 128; off > 0; off >>= 1) {
        if (t < off) s[t] += s[t + off];
        __syncthreads();
    }
    if (t == 0) bsums[b] = s[0];
}

__global__ __launch_bounds__(256) void scan_bsums(int* __restrict__ bsums, int nb) {
    __shared__ int s[256];
    __shared__ int carry_s;
    int t = threadIdx.x;
    if (t == 0) carry_s = 0;
    __syncthreads();
    for (int base = 0; base < nb; base += 256) {
        int idx = base + t;
        int v = (idx < nb) ? bsums[idx] : 0;
        s[t] = v; __syncthreads();
        for (int off = 1; off < 256; off <<= 1) {
            int x = (t >= off) ? s[t - off] : 0;
            __syncthreads();
            s[t] += x;
            __syncthreads();
        }
        int incl = s[t];
        int excl = incl - v;
        int c = carry_s;
        __syncthreads();
        if (idx < nb) bsums[idx] = c + excl;
        if (t == 255) carry_s = c + incl;
        __syncthreads();
    }
}

__global__ __launch_bounds__(256) void scan_apply(const int* __restrict__ in,
                                                  const int* __restrict__ boffs,
                                                  int* __restrict__ out, int n) {
    __shared__ int s[256];
    int b = blockIdx.x, t = threadIdx.x;
    int idx0 = b * SCAN_B + t * 4;
    int v[4]; int tsum = 0;
    #pragma unroll
    for (int k = 0; k < 4; ++k) {
        int idx = idx0 + k;
        v[k] = (idx < n) ? in[idx] : 0;
        tsum += v[k];
    }
    s[t] = tsum; __syncthreads();
    for (int off = 1; off < 256; off <<= 1) {
        int x = (t >= off) ? s[t - off] : 0;
        __syncthreads();
        s[t] += x;
        __syncthreads();
    }
    int run = s[t] - tsum + boffs[b];
    #pragma unroll
    for (int k = 0; k < 4; ++k) {
        int idx = idx0 + k;
        if (idx < n) out[idx] = run;
        run += v[k];
    }
}

// ---- K1: per-block coarse histograms of dst>>8 and src>>8 (LDS atomics only) ----
__global__ __launch_bounds__(256) void coarse_hist_kernel(
        const int* __restrict__ src, const int* __restrict__ dst,
        int* __restrict__ cntD, int* __restrict__ cntS, int E, int nbkt) {
    __shared__ int hD[MAXBKT];
    __shared__ int hS[MAXBKT];
    int bb = blockIdx.x, t = threadIdx.x;
    for (int k = t; k < MAXBKT; k += 256) { hD[k] = 0; hS[k] = 0; }
    __syncthreads();
    int chunk = E / NBLK;                 // exact
    int beg = bb * chunk, end = beg + chunk;
    for (int i = beg + t; i < end; i += 256) {
        atomicAdd(&hD[((unsigned)dst[i]) >> 8], 1);
        atomicAdd(&hS[((unsigned)src[i]) >> 8], 1);
    }
    __syncthreads();
    for (int k = t; k < nbkt; k += 256) {
        cntD[k * NBLK + bb] = hD[k];
        cntS[k * NBLK + bb] = hS[k];
    }
}

// ---- K2: scatter edges into dst-buckets (pairs) and src values into src-buckets ----
__global__ __launch_bounds__(256) void scatter_kernel(
        const int* __restrict__ src, const int* __restrict__ dst,
        const int* __restrict__ cntD, const int* __restrict__ cntS,
        uint2* __restrict__ pairs, int* __restrict__ sbuf, int E, int nbkt) {
    __shared__ int cD[MAXBKT];
    __shared__ int cS[MAXBKT];
    int bb = blockIdx.x, t = threadIdx.x;
    for (int k = t; k < nbkt; k += 256) {
        cD[k] = cntD[k * NBLK + bb];
        cS[k] = cntS[k * NBLK + bb];
    }
    __syncthreads();
    int chunk = E / NBLK;
    int beg = bb * chunk, end = beg + chunk;
    for (int i = beg + t; i < end; i += 256) {
        unsigned s = (unsigned)src[i], d = (unsigned)dst[i];
        int pD = atomicAdd(&cD[d >> 8], 1);
        pairs[pD] = make_uint2(s, d);
        int pS = atomicAdd(&cS[s >> 8], 1);
        sbuf[pS] = (int)s;
    }
}

// ---- K3a: per-bucket exact histogram of src values -> deg_out ----
__global__ __launch_bounds__(256) void bucket_deg_kernel(
        const int* __restrict__ sbuf, const int* __restrict__ cntS,
        int* __restrict__ deg_out, int N, int E, int nbkt) {
    __shared__ int hist[256];
    int b = blockIdx.x, t = threadIdx.x;
    int base = cntS[b * NBLK];
    int end = (b + 1 < nbkt) ? cntS[(b + 1) * NBLK] : E;
    hist[t] = 0; __syncthreads();
    for (int i = base + t; i < end; i += 256)
        atomicAdd(&hist[sbuf[i] & 255], 1);
    __syncthreads();
    int node = (b << 8) + t;
    if (node < N) deg_out[node] = hist[t];
}

// ---- K3b: per-bucket CSR build: row_start, deg_in, csr_src, csr_w ----
__global__ __launch_bounds__(256) void bucket_csr_kernel(
        const uint2* __restrict__ pairs, const int* __restrict__ cntD,
        const float* __restrict__ norm_out,
        int* __restrict__ row_start, int* __restrict__ deg_in,
        int* __restrict__ csr_src, float* __restrict__ csr_w,
        int N, int E, int nbkt) {
    __shared__ int hist[256];
    __shared__ int sc[256];
    __shared__ int cur[256];
    int b = blockIdx.x, t = threadIdx.x;
    int base = cntD[b * NBLK];
    int end = (b + 1 < nbkt) ? cntD[(b + 1) * NBLK] : E;
    hist[t] = 0; __syncthreads();
    for (int i = base + t; i < end; i += 256)
        atomicAdd(&hist[pairs[i].y & 255], 1);
    __syncthreads();
    int v = hist[t];
    sc[t] = v; __syncthreads();
    for (int off = 1; off < 256; off <<= 1) {
        int x = (t >= off) ? sc[t - off] : 0;
        __syncthreads();
        sc[t] += x;
        __syncthreads();
    }
    int ex = sc[t] - v;                  // exclusive in-bucket offset
    cur[t] = base + ex;
    int node = (b << 8) + t;
    if (node < N) { row_start[node] = base + ex; deg_in[node] = v; }
    __syncthreads();
    for (int i = base + t; i < end; i += 256) {
        uint2 p = pairs[i];
        int pos = atomicAdd(&cur[p.y & 255], 1);
        csr_src[pos] = (int)p.x;
        csr_w[pos] = norm_out[p.x];
    }
}

// ---- prep: fp32 -> bf16 elementwise (vectorized x4) ----
__global__ void cvt_bf16_kernel(const float* __restrict__ in, unsigned short* __restrict__ out,
                                int n4) {
    int i = blockIdx.x * blockDim.x + threadIdx.x;
    if (i >= n4) return;
    float4 v = reinterpret_cast<const float4*>(in)[i];
    unsigned short o[4] = { f2bf(v.x), f2bf(v.y), f2bf(v.z), f2bf(v.w) };
    reinterpret_cast<uint2*>(out)[i] = *reinterpret_cast<uint2*>(o);
}

// ---- prep: W [K][128] fp32 -> Wt [128][K] bf16 ----
__global__ void wt_transpose_kernel(const float* __restrict__ W, unsigned short* __restrict__ Wt,
                                    int K) {
    int i = blockIdx.x * blockDim.x + threadIdx.x;
    if (i >= 128 * K) return;
    int col = i / K, k = i % K;
    Wt[i] = f2bf(W[k * 128 + col]);
}

// ---- gather-aggregate (bf16 x): agg16[n] = f2bf(norm_in[n] * sum_e w_e * x[src_e]) ----
template<int TPG, int FIN>   // TPG = FIN/8
__global__ __launch_bounds__(256) void csr_agg_kernel(
        const unsigned short* __restrict__ x, const int* __restrict__ row_start,
        const int* __restrict__ deg, const int* __restrict__ csr_src,
        const float* __restrict__ csr_w, const float* __restrict__ norm_in,
        unsigned short* __restrict__ agg, int N) {
    const int GPB = 256 / TPG;
    int g = threadIdx.x / TPG;
    int j = threadIdx.x % TPG;
    int n = blockIdx.x * GPB + g;
    if (n >= N) return;
    int beg = row_start[n];
    int end = beg + deg[n];
    float acc[8] = {0.f, 0.f, 0.f, 0.f, 0.f, 0.f, 0.f, 0.f};
    for (int e = beg; e < end; ++e) {
        int s = csr_src[e];
        float w = csr_w[e];
        float4 raw = *reinterpret_cast<const float4*>(&x[(size_t)s * FIN + j * 8]);
        const unsigned short* u = reinterpret_cast<const unsigned short*>(&raw);
        #pragma unroll
        for (int t = 0; t < 8; ++t)
            acc[t] += w * bf2f(u[t]);
    }
    float nin = norm_in[n];
    unsigned short ov[8];
    #pragma unroll
    for (int t = 0; t < 8; ++t) ov[t] = f2bf(acc[t] * nin);
    *reinterpret_cast<float4*>(&agg[(size_t)n * FIN + j * 8]) = *reinterpret_cast<float4*>(ov);
}

// ---- MFMA node GEMM (128x128 tile, 4 waves, 16x16x32 bf16) ----
template<int FIN, bool SELU, bool OUT_BF16>
__global__ __launch_bounds__(256, 2) void gemm_mfma_kernel(
        const unsigned short* __restrict__ agg16,
        const unsigned short* __restrict__ Wt,
        const float* __restrict__ b,
        void* __restrict__ out,
        int N) {
    const int PAD = 8;
    const int LDA = FIN + PAD;
    __shared__ unsigned short sA[128 * LDA];
    __shared__ unsigned short sW[128 * LDA];
    const int tid = threadIdx.x;
    const int wave = tid >> 6, lane = tid & 63;
    const int wr = (wave >> 1) * 64;
    const int wc = (wave & 1) * 64;
    const int n0 = blockIdx.x * 128;
    const int CH = FIN / 8;

    for (int i = tid; i < 128 * CH; i += 256) {
        int col = i / CH, kc = i % CH;
        *reinterpret_cast<float4*>(&sW[col * LDA + kc * 8]) =
            *reinterpret_cast<const float4*>(&Wt[col * FIN + kc * 8]);
    }
    for (int i = tid; i < 128 * CH; i += 256) {
        int node = i / CH, kc = i % CH;
        int n = n0 + node;
        float4 v = make_float4(0.f, 0.f, 0.f, 0.f);
        if (n < N)
            v = *reinterpret_cast<const float4*>(&agg16[(size_t)n * FIN + kc * 8]);
        *reinterpret_cast<float4*>(&sA[node * LDA + kc * 8]) = v;
    }
    __syncthreads();

    const int l16 = lane & 15;
    const int lk = (lane >> 4) * 8;
    f32x4 acc[4][4];
    #pragma unroll
    for (int mi = 0; mi < 4; ++mi)
        #pragma unroll
        for (int ci = 0; ci < 4; ++ci)
            acc[mi][ci] = (f32x4){0.f, 0.f, 0.f, 0.f};

    #pragma unroll
    for (int k0 = 0; k0 < FIN; k0 += 32) {
        bf16x8 a[4], w[4];
        #pragma unroll
        for (int mi = 0; mi < 4; ++mi)
            a[mi] = *reinterpret_cast<const bf16x8*>(&sA[(wr + mi * 16 + l16) * LDA + k0 + lk]);
        #pragma unroll
        for (int ci = 0; ci < 4; ++ci)
            w[ci] = *reinterpret_cast<const bf16x8*>(&sW[(wc + ci * 16 + l16) * LDA + k0 + lk]);
        #pragma unroll
        for (int mi = 0; mi < 4; ++mi)
            #pragma unroll
            for (int ci = 0; ci < 4; ++ci)
                acc[mi][ci] = __builtin_amdgcn_mfma_f32_16x16x32_bf16(
                    a[mi], w[ci], acc[mi][ci], 0, 0, 0);
    }

    const int rbase = (lane >> 4) * 4;
    #pragma unroll
    for (int ci = 0; ci < 4; ++ci) {
        int col = wc + ci * 16 + l16;
        float bias = b[col];
        #pragma unroll
        for (int mi = 0; mi < 4; ++mi) {
            #pragma unroll
            for (int r = 0; r < 4; ++r) {
                int n = n0 + wr + mi * 16 + rbase + r;
                if (n < N) {
                    float v = acc[mi][ci][r] + bias;
                    if (SELU) v = selu_f(v);
                    if (OUT_BF16)
                        ((unsigned short*)out)[(size_t)n * 128 + col] = f2bf(v);
                    else
                        ((float*)out)[(size_t)n * 128 + col] = v;
                }
            }
        }
    }
}

// ---- graph range starts (node2graph sorted) ----
__global__ void graph_starts_kernel(const int* __restrict__ n2g, int* __restrict__ gstart,
                                    int N, int G) {
    int g = blockIdx.x * blockDim.x + threadIdx.x;
    if (g > G) return;
    int lo = 0, hi = N;
    while (lo < hi) {
        int mid = (lo + hi) >> 1;
        if (n2g[mid] < g) lo = mid + 1; else hi = mid;
    }
    gstart[g] = lo;
}

// ---- readout from bf16 y ----
__global__ __launch_bounds__(128) void readout_kernel(
        const unsigned short* __restrict__ y, const int* __restrict__ gstart,
        float* __restrict__ gsum, int G) {
    int g = blockIdx.x;
    int o = threadIdx.x;
    if (g >= G) return;
    int beg = gstart[g], end = gstart[g + 1];
    float acc = 0.f;
    for (int n = beg; n < end; ++n)
        acc += bf2f(y[(size_t)n * 128 + o]);
    gsum[(size_t)g * 128 + o] = acc;
}

// ---- MLP head (fp32) ----
__global__ __launch_bounds__(256) void mlp1_kernel(
        const float* __restrict__ gsum, const float* __restrict__ fg,
        const float* __restrict__ W, const float* __restrict__ b,
        float* __restrict__ y1, int G) {
    int g = blockIdx.x;
    int o = threadIdx.x;
    if (g >= G) return;
    float acc = b[o];
    const float* in = gsum + (size_t)g * 128;
    #pragma unroll 8
    for (int k = 0; k < 128; ++k) acc += in[k] * W[k * 256 + o];
    const float* fgr = fg + (size_t)g * 3;
    acc += fgr[0] * W[128 * 256 + o];
    acc += fgr[1] * W[129 * 256 + o];
    acc += fgr[2] * W[130 * 256 + o];
    y1[(size_t)g * 256 + o] = selu_f(acc);
}

__global__ __launch_bounds__(128) void mlp2_kernel(
        const float* __restrict__ y1, const float* __restrict__ W,
        const float* __restrict__ b, float* __restrict__ y2, int G) {
    int g = blockIdx.x;
    int o = threadIdx.x;
    if (g >= G) return;
    float acc = b[o];
    const float* in = y1 + (size_t)g * 256;
    #pragma unroll 8
    for (int k = 0; k < 256; ++k) acc += in[k] * W[k * 128 + o];
    y2[(size_t)g * 128 + o] = selu_f(acc);
}

__global__ void mlp3_kernel(const float* __restrict__ y2, const float* __restrict__ W,
                            const float* __restrict__ b, float* __restrict__ out, int G) {
    int g = blockIdx.x * blockDim.x + threadIdx.x;
    if (g >= G) return;
    const float* in = y2 + (size_t)g * 128;
    float acc = b[0];
    #pragma unroll 8
    for (int k = 0; k < 128; ++k) acc += in[k] * W[k];
    out[g] = acc;
}

extern "C" void kernel_launch(void* const* d_in, const int* in_sizes, int n_in,
                              void* d_out, int out_size, void* d_ws, size_t ws_size,
                              hipStream_t stream) {
    const float* feats_node  = (const float*)d_in[0];
    const float* feats_graph = (const float*)d_in[1];
    const int*   src         = (const int*)d_in[2];
    const int*   dst         = (const int*)d_in[3];
    const int*   node2graph  = (const int*)d_in[4];
    const float* W1 = (const float*)d_in[5];
    const float* b1 = (const float*)d_in[6];
    const float* W2 = (const float*)d_in[7];
    const float* b2 = (const float*)d_in[8];
    const float* W3 = (const float*)d_in[9];
    const float* b3 = (const float*)d_in[10];
    const float* L1w = (const float*)d_in[11];
    const float* L1b = (const float*)d_in[12];
    const float* L2w = (const float*)d_in[13];
    const float* L2b = (const float*)d_in[14];
    const float* L3w = (const float*)d_in[15];
    const float* L3b = (const float*)d_in[16];

    const int N = in_sizes[0] / 64;
    const int G = in_sizes[1] / 3;
    const int E = in_sizes[2];
    const int NBKT = (N + 255) >> 8;           // 391 for N=100000
    const int nmat = NBKT * NBLK;              // count-matrix elements
    const int NBsc = (nmat + SCAN_B - 1) / SCAN_B;

    // ---- workspace layout ----
    int* iws = (int*)d_ws;
    int* deg_out_i = iws;                      // N
    int* deg_in_i  = deg_out_i + N;            // N
    int* row_start = deg_in_i + N;             // N
    int* bsums     = row_start + N;            // 512
    int* gstart    = bsums + 512;              // G+8
    int* cntD      = gstart + (G + 8);         // nmat
    int* cntS      = cntD + nmat;              // nmat
    int* csr_src   = cntS + nmat;              // E

    float* norm_out = (float*)(csr_src + E);   // N
    float* norm_in  = norm_out + N;            // N
    float* csr_w    = norm_in + N;             // E

    unsigned short* feats16 = (unsigned short*)(csr_w + E);       // N*64
    unsigned short* x16     = feats16 + (size_t)N * 64;           // N*128
    unsigned short* agg16   = x16 + (size_t)N * 128;              // N*128
    unsigned short* y16     = agg16 + (size_t)N * 128;            // N*128
    unsigned short* Wt1     = y16 + (size_t)N * 128;              // 128*64
    unsigned short* Wt2     = Wt1 + 128 * 64;                     // 128*128
    unsigned short* Wt3     = Wt2 + 128 * 128;                    // 128*128

    float* gsum = (float*)(Wt3 + 128 * 128);   // G*128
    float* y1   = gsum + (size_t)G * 128;      // G*256
    float* y2   = y1 + (size_t)G * 256;        // G*128

    // pairs/sbuf alias y16 (dead until layer-3 output); align to 16B
    uint2* pairs = (uint2*)(((uintptr_t)y16 + 15) & ~(uintptr_t)15);  // E uint2
    int*   sbuf  = (int*)(pairs + E);                                  // E ints

    float* out = (float*)d_out;

    // ---- 0. prep: bf16 conversions + W transposes ----
    cvt_bf16_kernel<<<(N * 16 + 255) / 256, 256, 0, stream>>>(feats_node, feats16, N * 16);
    wt_transpose_kernel<<<(128 * 64 + 255) / 256, 256, 0, stream>>>(W1, Wt1, 64);
    wt_transpose_kernel<<<(128 * 128 + 255) / 256, 256, 0, stream>>>(W2, Wt2, 128);
    wt_transpose_kernel<<<(128 * 128 + 255) / 256, 256, 0, stream>>>(W3, Wt3, 128);

    // ---- 1. bucket partition (no global atomics) ----
    coarse_hist_kernel<<<NBLK, 256, 0, stream>>>(src, dst, cntD, cntS, E, NBKT);
    scan_block_sums<<<NBsc, 256, 0, stream>>>(cntD, bsums, nmat);
    scan_bsums<<<1, 256, 0, stream>>>(bsums, NBsc);
    scan_apply<<<NBsc, 256, 0, stream>>>(cntD, bsums, cntD, nmat);
    scan_block_sums<<<NBsc, 256, 0, stream>>>(cntS, bsums, nmat);
    scan_bsums<<<1, 256, 0, stream>>>(bsums, NBsc);
    scan_apply<<<NBsc, 256, 0, stream>>>(cntS, bsums, cntS, nmat);
    scatter_kernel<<<NBLK, 256, 0, stream>>>(src, dst, cntD, cntS, pairs, sbuf, E, NBKT);

    // ---- 2. degrees / norms / CSR ----
    bucket_deg_kernel<<<NBKT, 256, 0, stream>>>(sbuf, cntS, deg_out_i, N, E, NBKT);
    norm_kernel<<<(N + 255) / 256, 256, 0, stream>>>(deg_out_i, norm_out, N);
    bucket_csr_kernel<<<NBKT, 256, 0, stream>>>(
        pairs, cntD, norm_out, row_start, deg_in_i, csr_src, csr_w, N, E, NBKT);
    norm_kernel<<<(N + 255) / 256, 256, 0, stream>>>(deg_in_i, norm_in, N);

    const int gemm_grid = (N + 127) / 128;

    // ---- 3. layer 1 (FIN=64) ----
    csr_agg_kernel<8, 64><<<(N + 31) / 32, 256, 0, stream>>>(
        feats16, row_start, deg_in_i, csr_src, csr_w, norm_in, agg16, N);
    gemm_mfma_kernel<64, true, true><<<gemm_grid, 256, 0, stream>>>(
        agg16, Wt1, b1, x16, N);

    // ---- 4. layer 2 (FIN=128) ----
    csr_agg_kernel<16, 128><<<(N + 15) / 16, 256, 0, stream>>>(
        x16, row_start, deg_in_i, csr_src, csr_w, norm_in, agg16, N);
    gemm_mfma_kernel<128, true, true><<<gemm_grid, 256, 0, stream>>>(
        agg16, Wt2, b2, x16, N);

    // ---- 5. layer 3 (FIN=128, no selu; y16 written AFTER pairs/sbuf are dead) ----
    csr_agg_kernel<16, 128><<<(N + 15) / 16, 256, 0, stream>>>(
        x16, row_start, deg_in_i, csr_src, csr_w, norm_in, agg16, N);
    gemm_mfma_kernel<128, false, true><<<gemm_grid, 256, 0, stream>>>(
        agg16, Wt3, b3, y16, N);

    // ---- 6. readout ----
    graph_starts_kernel<<<(G + 1 + 255) / 256, 256, 0, stream>>>(node2graph, gstart, N, G);
    readout_kernel<<<G, 128, 0, stream>>>(y16, gstart, gsum, G);

    // ---- 7. MLP head ----
    mlp1_kernel<<<G, 256, 0, stream>>>(gsum, feats_graph, L1w, L1b, y1, G);
    mlp2_kernel<<<G, 128, 0, stream>>>(y1, L2w, L2b, y2, G);
    mlp3_kernel<<<(G + 255) / 256, 256, 0, stream>>>(y2, L3w, L3b, out, G);
}